// Round 4
// baseline (2688.688 us; speedup 1.0000x reference)
//
#include <hip/hip_runtime.h>
#include <hip/hip_bf16.h>

// VQVAE forward: B=1024, IN=256, H=512, E=512, NE=8192, T=32.
// MFMA split-bf16 (hi/lo) path for convs + FCs; fp32 VALU for VQ scoring.

#define B_ 1024
#define IN_ 256
#define H_ 512
#define E_ 512
#define NE_ 8192
#define T_ 32

typedef __attribute__((ext_vector_type(8))) short short8;
typedef __attribute__((ext_vector_type(4))) short short4v;
typedef __attribute__((ext_vector_type(4))) float f32x4;

__device__ __forceinline__ unsigned short bf_hi(float v) {
    __hip_bfloat16 h = __float2bfloat16(v);
    return *reinterpret_cast<unsigned short*>(&h);
}
__device__ __forceinline__ float bf_f(unsigned short u) {
    __hip_bfloat16 h;
    *reinterpret_cast<unsigned short*>(&h) = u;
    return __bfloat162float(h);
}
__device__ __forceinline__ void split2(float v, unsigned short& h, unsigned short& l) {
    h = bf_hi(v);
    l = bf_hi(v - bf_f(h));
}

// ---------------- transpose + hi/lo split ----------------
// src: [outer][R=256*chunks][32] fp32 -> dst planes [outer][32][R] bf16 hi/lo
__global__ __launch_bounds__(256) void transpose_split(const float* __restrict__ src,
        unsigned short* __restrict__ dh, unsigned short* __restrict__ dl,
        int chunks, size_t s_outer, size_t d_outer, int d_rstride) {
    __shared__ float xs[256][33];
    const int ch = blockIdx.x % chunks;
    const int ou = blockIdx.x / chunks;
    const int tid = threadIdx.x;
    const float4* s4 = (const float4*)(src + (size_t)ou * s_outer + (size_t)ch * 256 * 32);
#pragma unroll
    for (int q = 0; q < 8; ++q) {
        float4 v = s4[tid * 8 + q];
        xs[tid][q * 4 + 0] = v.x;
        xs[tid][q * 4 + 1] = v.y;
        xs[tid][q * 4 + 2] = v.z;
        xs[tid][q * 4 + 3] = v.w;
    }
    __syncthreads();
    const int t = tid & 31, ig = tid >> 5;
#pragma unroll
    for (int g2 = 0; g2 < 4; ++g2) {
        int i0 = (ig + g2 * 8) * 8;
        short8 hv, lv;
#pragma unroll
        for (int j = 0; j < 8; ++j) {
            float v = xs[i0 + j][t];
            unsigned short hh, ll;
            split2(v, hh, ll);
            hv[j] = (short)hh;
            lv[j] = (short)ll;
        }
        size_t off = (size_t)ou * d_outer + (size_t)ch * 256 + (size_t)t * d_rstride + i0;
        *(short8*)(dh + off) = hv;
        *(short8*)(dl + off) = lv;
    }
}

// ---------------- weight preps ----------------
__global__ void wprep_conv(const float* __restrict__ w, unsigned short* __restrict__ wh,
                           unsigned short* __restrict__ wl, int O, int I) {
    int t = blockIdx.x * 256 + threadIdx.x;
    if (t < O * I) {
        int OI = O * I;
#pragma unroll
        for (int tap = 0; tap < 3; ++tap) {
            float v = w[(size_t)t * 3 + tap];
            unsigned short hh, ll;
            split2(v, hh, ll);
            wh[(size_t)tap * OI + t] = hh;
            wl[(size_t)tap * OI + t] = ll;
        }
    }
}
__global__ void wprep_deconv(const float* __restrict__ w, unsigned short* __restrict__ wh,
                             unsigned short* __restrict__ wl, int O, int I) {
    int t = blockIdx.x * 256 + threadIdx.x;
    if (t < O * I) {
        int o = t / I, i = t % I;
        int OI = O * I;
#pragma unroll
        for (int tap = 0; tap < 3; ++tap) {
            float v = w[((size_t)i * O + o) * 3 + 2 - tap];
            unsigned short hh, ll;
            split2(v, hh, ll);
            wh[(size_t)tap * OI + t] = hh;
            wl[(size_t)tap * OI + t] = ll;
        }
    }
}
__global__ void wprep_dfw(const float* __restrict__ w, unsigned short* __restrict__ wh,
                          unsigned short* __restrict__ wl) {
    size_t id = (size_t)blockIdx.x * 256 + threadIdx.x;
    int fp = (int)(id >> 6);
    int e8 = ((int)id & 63) * 8;
    int tt = fp >> 9, c = fp & 511;
    int f = c * 32 + tt;
    const float* s = w + (size_t)f * 512 + e8;
    short8 hv, lv;
#pragma unroll
    for (int j = 0; j < 8; ++j) {
        unsigned short hh, ll;
        split2(s[j], hh, ll);
        hv[j] = (short)hh;
        lv[j] = (short)ll;
    }
    *(short8*)(wh + (size_t)fp * 512 + e8) = hv;
    *(short8*)(wl + (size_t)fp * 512 + e8) = lv;
}
__global__ void wprep_dfb(const float* __restrict__ b, float* __restrict__ bp) {
    int fp = blockIdx.x * 256 + threadIdx.x;
    int tt = fp >> 9, c = fp & 511;
    bp[fp] = b[c * 32 + tt];
}

// ---------------- conv1d via MFMA implicit GEMM ----------------
// Acts: planes [b][t][CIN] bf16 hi/lo. Weights: [tap][o][i] hi/lo.
// Block = 2 batches (64 cols), 8 waves, 512 blocks total (2 blocks/CU).
template <int CIN, int COUT, bool FP32OUT>
__global__ __launch_bounds__(512, 4) void conv_mfma(
    const unsigned short* __restrict__ Xh, const unsigned short* __restrict__ Xl,
    const unsigned short* __restrict__ Wh, const unsigned short* __restrict__ Wl,
    const float* __restrict__ bias,
    unsigned short* __restrict__ Yh, unsigned short* __restrict__ Yl,
    float* __restrict__ Yf) {
    constexpr int NSTEP = CIN / 32;
    constexpr int NF = (COUT == 512) ? 4 : 2;
    __shared__ short Bs[2][2][68][36];  // 39.1 KB, stride 36 = conflict-free

    const int tid = threadIdx.x;
    const int wid = tid >> 6;
    const int lane = tid & 63;
    const int l15 = lane & 15;
    const int lg = lane >> 4;
    const int b0 = blockIdx.x * 2;

    const int of_base = (COUT == 512) ? wid * 64 : (wid & 3) * 64;
    const int nf0 = (COUT == 512) ? 0 : (wid >> 2) * 2;

    // zero the 16 pad rows (t=-1 / t=32 per batch, both buffers/planes)
    for (int j = tid; j < 16 * 36; j += 512) {
        int r = j / 36, c = j % 36;
        int buf = r >> 3, pl = (r >> 2) & 1, g = (r >> 1) & 1, e = r & 1;
        Bs[buf][pl][g * 34 + e * 33][c] = 0;
    }

    f32x4 acc[4][NF];
#pragma unroll
    for (int of = 0; of < 4; ++of)
#pragma unroll
        for (int nf = 0; nf < NF; ++nf) acc[of][nf] = (f32x4){0.f, 0.f, 0.f, 0.f};

    // staging map: 512 threads -> 64 rows x 2 planes x 4 i-quads
    const int rp = tid >> 2;
    const int sq = tid & 3;
    const int sb = rp >> 6;
    const int spl = (rp >> 5) & 1;
    const int st = rp & 31;
    const unsigned short* sbase =
        (spl ? Xl : Xh) + (((size_t)(b0 + sb) * 32) + st) * CIN + sq * 8;
    const int srow = sb * 34 + 1 + st;

    *(short8*)&Bs[0][spl][srow][sq * 8] = *(const short8*)(sbase);
    __syncthreads();

    for (int ks = 0; ks < NSTEP; ++ks) {
        const int i0 = ks * 32;
        const int buf = ks & 1;
        const bool pre = (ks + 1 < NSTEP);
        short8 nv;
        if (pre) nv = *(const short8*)(sbase + i0 + 32);
#pragma unroll
        for (int tap = 0; tap < 3; ++tap) {
            short8 Ah[4], Al[4];
#pragma unroll
            for (int of = 0; of < 4; ++of) {
                const size_t wo =
                    ((size_t)tap * COUT + of_base + of * 16 + l15) * CIN + i0 + lg * 8;
                Ah[of] = *(const short8*)(Wh + wo);
                Al[of] = *(const short8*)(Wl + wo);
            }
            __builtin_amdgcn_s_setprio(1);
#pragma unroll
            for (int nf = 0; nf < NF; ++nf) {
                const int nfg = nf0 + nf;
                const int row = (nfg >> 1) * 34 + (nfg & 1) * 16 + tap + l15;
                short8 Bh = *(const short8*)&Bs[buf][0][row][lg * 8];
                short8 Bl = *(const short8*)&Bs[buf][1][row][lg * 8];
#pragma unroll
                for (int of = 0; of < 4; ++of) {
                    acc[of][nf] =
                        __builtin_amdgcn_mfma_f32_16x16x32_bf16(Ah[of], Bh, acc[of][nf], 0, 0, 0);
                    acc[of][nf] =
                        __builtin_amdgcn_mfma_f32_16x16x32_bf16(Ah[of], Bl, acc[of][nf], 0, 0, 0);
                    acc[of][nf] =
                        __builtin_amdgcn_mfma_f32_16x16x32_bf16(Al[of], Bh, acc[of][nf], 0, 0, 0);
                }
            }
            __builtin_amdgcn_s_setprio(0);
        }
        if (pre) {
            *(short8*)&Bs[buf ^ 1][spl][srow][sq * 8] = nv;
            __syncthreads();
        }
    }

    // epilogue: lane holds cols n (per nf), rows m = of*16 + 4*lg + r
#pragma unroll
    for (int of = 0; of < 4; ++of) {
        const int m4 = of_base + of * 16 + lg * 4;
        float4 bv = *(const float4*)(bias + m4);
        float bva[4] = {bv.x, bv.y, bv.z, bv.w};
#pragma unroll
        for (int nf = 0; nf < NF; ++nf) {
            const int n = (nf0 + nf) * 16 + l15;
            const int gb = b0 + (n >> 5);
            const int t = n & 31;
            if (FP32OUT) {
#pragma unroll
                for (int r = 0; r < 4; ++r) {
                    float v = acc[of][nf][r] + bva[r];
                    Yf[((size_t)gb * COUT + m4 + r) * 32 + t] = v;
                }
            } else {
                short4v hv, lv;
#pragma unroll
                for (int r = 0; r < 4; ++r) {
                    float v = fmaxf(acc[of][nf][r] + bva[r], 0.f);
                    unsigned short hh, ll;
                    split2(v, hh, ll);
                    hv[r] = (short)hh;
                    lv[r] = (short)ll;
                }
                const size_t off = ((size_t)gb * 32 + t) * COUT + m4;
                *(short4v*)(Yh + off) = hv;
                *(short4v*)(Yl + off) = lv;
            }
        }
    }
}

// ---------------- FC via MFMA (global-fragment GEMM-TN) ----------------
// C[m,n] = sum_k A[m,k]*B[n,k], 3-term split. Block: 256 m x 128 n, 8 waves.
// MODE 0: fp32 partial [kz][n][m]; MODE 1: +bias, hi/lo out [n][m].
template <int MODE>
__global__ __launch_bounds__(512) void fc_mfma(
    const unsigned short* __restrict__ Ah_, const unsigned short* __restrict__ Al_,
    const unsigned short* __restrict__ Bh_, const unsigned short* __restrict__ Bl_,
    const float* __restrict__ bias, float* __restrict__ Pf,
    unsigned short* __restrict__ Oh, unsigned short* __restrict__ Ol,
    int M, int N, int K, int kc) {
    const int tid = threadIdx.x;
    const int wid = tid >> 6;
    const int lane = tid & 63;
    const int l15 = lane & 15;
    const int lg = lane >> 4;
    const int m0 = blockIdx.y * 256 + (wid & 3) * 64;
    const int n0 = blockIdx.x * 128 + (wid >> 2) * 64;
    const int k0b = blockIdx.z * kc;

    f32x4 acc[4][4];
#pragma unroll
    for (int of = 0; of < 4; ++of)
#pragma unroll
        for (int nf = 0; nf < 4; ++nf) acc[of][nf] = (f32x4){0.f, 0.f, 0.f, 0.f};

    for (int k0 = k0b; k0 < k0b + kc; k0 += 32) {
        short8 Ah[4], Al[4];
#pragma unroll
        for (int of = 0; of < 4; ++of) {
            const size_t ao = (size_t)(m0 + of * 16 + l15) * K + k0 + lg * 8;
            Ah[of] = *(const short8*)(Ah_ + ao);
            Al[of] = *(const short8*)(Al_ + ao);
        }
#pragma unroll
        for (int nf = 0; nf < 4; ++nf) {
            const size_t bo = (size_t)(n0 + nf * 16 + l15) * K + k0 + lg * 8;
            short8 Bh = *(const short8*)(Bh_ + bo);
            short8 Bl = *(const short8*)(Bl_ + bo);
#pragma unroll
            for (int of = 0; of < 4; ++of) {
                acc[of][nf] =
                    __builtin_amdgcn_mfma_f32_16x16x32_bf16(Ah[of], Bh, acc[of][nf], 0, 0, 0);
                acc[of][nf] =
                    __builtin_amdgcn_mfma_f32_16x16x32_bf16(Ah[of], Bl, acc[of][nf], 0, 0, 0);
                acc[of][nf] =
                    __builtin_amdgcn_mfma_f32_16x16x32_bf16(Al[of], Bh, acc[of][nf], 0, 0, 0);
            }
        }
    }

#pragma unroll
    for (int of = 0; of < 4; ++of) {
        const int m4 = m0 + of * 16 + lg * 4;
        if (MODE == 0) {
#pragma unroll
            for (int nf = 0; nf < 4; ++nf) {
                const int n = n0 + nf * 16 + l15;
                *(f32x4*)(Pf + ((size_t)blockIdx.z * N + n) * M + m4) = acc[of][nf];
            }
        } else {
            float4 bv = *(const float4*)(bias + m4);
            float bva[4] = {bv.x, bv.y, bv.z, bv.w};
#pragma unroll
            for (int nf = 0; nf < 4; ++nf) {
                const int n = n0 + nf * 16 + l15;
                short4v hv, lv;
#pragma unroll
                for (int r = 0; r < 4; ++r) {
                    float v = acc[of][nf][r] + bva[r];
                    unsigned short hh, ll;
                    split2(v, hh, ll);
                    hv[r] = (short)hh;
                    lv[r] = (short)ll;
                }
                *(short4v*)(Oh + (size_t)n * M + m4) = hv;
                *(short4v*)(Ol + (size_t)n * M + m4) = lv;
            }
        }
    }
}

// sum 32 split-K partials [kz][b][e] + bias -> z [b][e]
__global__ void reduce_bias32(const float4* __restrict__ part, const float* __restrict__ bias,
                              float4* __restrict__ z) {
    int t = blockIdx.x * 256 + threadIdx.x;
    const size_t stride = (size_t)B_ * E_ / 4;
    float4 a = part[t];
#pragma unroll 4
    for (int s = 1; s < 32; ++s) {
        float4 p = part[(size_t)s * stride + t];
        a.x += p.x;
        a.y += p.y;
        a.z += p.z;
        a.w += p.w;
    }
    float4 bv = ((const float4*)bias)[t & (E_ / 4 - 1)];
    a.x += bv.x;
    a.y += bv.y;
    a.z += bv.z;
    a.w += bv.w;
    z[t] = a;
}

// ---------------- VQ (fp32, validated) ----------------
__global__ void cnorm_k(const float* __restrict__ cb, float* __restrict__ cnorm) {
    int n = blockIdx.x;
    int l = threadIdx.x;
    const float4* row = (const float4*)(cb + (size_t)n * E_);
    float s = 0.f;
#pragma unroll
    for (int q = 0; q < 2; ++q) {
        float4 v = row[l + q * 64];
        s += v.x * v.x + v.y * v.y + v.z * v.z + v.w * v.w;
    }
#pragma unroll
    for (int off = 32; off; off >>= 1) s += __shfl_down(s, off);
    if (l == 0) cnorm[n] = s;
}

__global__ __launch_bounds__(256) void vq_score(const float* __restrict__ z,
                                                const float* __restrict__ cb,
                                                const float* __restrict__ cnorm,
                                                float* __restrict__ pval, int* __restrict__ pidx) {
    __shared__ __align__(16) float smem[2 * 16 * 132];
    float(*As)[132] = (float(*)[132])smem;
    float(*Bsh)[132] = (float(*)[132])(smem + 16 * 132);
    const int n0 = blockIdx.x * 128;
    const int m0 = blockIdx.y * 128;
    const int tid = threadIdx.x;
    const int tx = tid & 15;
    const int ty = tid >> 4;
    float acc[8][8] = {};

    for (int k0 = 0; k0 < E_; k0 += 16) {
#pragma unroll
        for (int l = 0; l < 2; ++l) {
            int t = tid + l * 256;
            int r = t >> 2;
            int c = (t & 3) << 2;
            float4 va = *(const float4*)(z + (size_t)(m0 + r) * E_ + k0 + c);
            As[c + 0][r] = va.x;
            As[c + 1][r] = va.y;
            As[c + 2][r] = va.z;
            As[c + 3][r] = va.w;
            float4 vb = *(const float4*)(cb + (size_t)(n0 + r) * E_ + k0 + c);
            Bsh[c + 0][r] = vb.x;
            Bsh[c + 1][r] = vb.y;
            Bsh[c + 2][r] = vb.z;
            Bsh[c + 3][r] = vb.w;
        }
        __syncthreads();
#pragma unroll
        for (int k = 0; k < 16; ++k) {
            float a[8], b[8];
            *(float4*)&a[0] = *(const float4*)&As[k][ty * 8];
            *(float4*)&a[4] = *(const float4*)&As[k][ty * 8 + 4];
            *(float4*)&b[0] = *(const float4*)&Bsh[k][tx * 8];
            *(float4*)&b[4] = *(const float4*)&Bsh[k][tx * 8 + 4];
#pragma unroll
            for (int i = 0; i < 8; ++i)
#pragma unroll
                for (int j = 0; j < 8; ++j) acc[i][j] += a[i] * b[j];
        }
        __syncthreads();
    }

    float* sv = smem;
    int* si = (int*)(smem + 16 * 132);
    float cn[8];
    *(float4*)&cn[0] = *(const float4*)(cnorm + n0 + tx * 8);
    *(float4*)&cn[4] = *(const float4*)(cnorm + n0 + tx * 8 + 4);
#pragma unroll
    for (int i = 0; i < 8; ++i) {
        int row = ty * 8 + i;
        float bvv = -3.4e38f;
        int bn = 0;
#pragma unroll
        for (int j = 0; j < 8; ++j) {
            float v = 2.f * acc[i][j] - cn[j];
            if (v > bvv) {
                bvv = v;
                bn = n0 + tx * 8 + j;
            }
        }
        sv[row * 16 + tx] = bvv;
        si[row * 16 + tx] = bn;
    }
    __syncthreads();
    if (tid < 128) {
        float bvv = sv[tid * 16];
        int bn = si[tid * 16];
#pragma unroll
        for (int t = 1; t < 16; ++t) {
            float v = sv[tid * 16 + t];
            if (v > bvv) {
                bvv = v;
                bn = si[tid * 16 + t];
            }
        }
        pval[(size_t)(m0 + tid) * 64 + blockIdx.x] = bvv;
        pidx[(size_t)(m0 + tid) * 64 + blockIdx.x] = bn;
    }
}

__global__ void vq_final(const float* __restrict__ pval, const int* __restrict__ pidx,
                         int* __restrict__ idx) {
    int b = blockIdx.x * 256 + threadIdx.x;
    if (b < B_) {
        const float* pv = pval + (size_t)b * 64;
        const int* pi = pidx + (size_t)b * 64;
        float bvv = pv[0];
        int bn = pi[0];
        for (int t = 1; t < 64; ++t) {
            float v = pv[t];
            if (v > bvv) {
                bvv = v;
                bn = pi[t];
            }
        }
        idx[b] = bn;
    }
}

__global__ __launch_bounds__(128) void zq_loss(const float* __restrict__ z,
                                               const float* __restrict__ cb,
                                               const int* __restrict__ idx,
                                               unsigned short* __restrict__ zqh,
                                               unsigned short* __restrict__ zql,
                                               float* __restrict__ lsum) {
    int b = blockIdx.x;
    int t = threadIdx.x;
    int id = idx[b];
    float4 c = ((const float4*)(cb + (size_t)id * E_))[t];
    float4 zv = ((const float4*)(z + (size_t)b * E_))[t];
    float ca[4] = {c.x, c.y, c.z, c.w};
    short4v hv, lv;
#pragma unroll
    for (int r = 0; r < 4; ++r) {
        unsigned short hh, ll;
        split2(ca[r], hh, ll);
        hv[r] = (short)hh;
        lv[r] = (short)ll;
    }
    *(short4v*)(zqh + (size_t)b * E_ + t * 4) = hv;
    *(short4v*)(zql + (size_t)b * E_ + t * 4) = lv;
    float dx = c.x - zv.x, dy = c.y - zv.y, dz = c.z - zv.z, dw = c.w - zv.w;
    float s = dx * dx + dy * dy + dz * dz + dw * dw;
#pragma unroll
    for (int off = 32; off; off >>= 1) s += __shfl_down(s, off);
    __shared__ float w2[2];
    if ((t & 63) == 0) w2[t >> 6] = s;
    __syncthreads();
    if (t == 0) lsum[b] = w2[0] + w2[1];
}

__global__ void loss_final(const float* __restrict__ lsum, float* __restrict__ out) {
    __shared__ float sm[256];
    float s = 0.f;
    for (int i = threadIdx.x; i < B_; i += 256) s += lsum[i];
    sm[threadIdx.x] = s;
    __syncthreads();
    for (int off = 128; off; off >>= 1) {
        if (threadIdx.x < off) sm[threadIdx.x] += sm[threadIdx.x + off];
        __syncthreads();
    }
    if (threadIdx.x == 0) out[0] = 1.25f * sm[0] / (float)(B_ * E_);
}

// ---------------- launcher ----------------
extern "C" void kernel_launch(void* const* d_in, const int* in_sizes, int n_in,
                              void* d_out, int out_size, void* d_ws, size_t ws_size,
                              hipStream_t stream) {
    const float* x = (const float*)d_in[0];
    const float* ew1 = (const float*)d_in[1];
    const float* eb1 = (const float*)d_in[2];
    const float* ew2 = (const float*)d_in[3];
    const float* eb2 = (const float*)d_in[4];
    const float* ew3 = (const float*)d_in[5];
    const float* eb3 = (const float*)d_in[6];
    const float* ew4 = (const float*)d_in[7];
    const float* eb4 = (const float*)d_in[8];
    const float* efw = (const float*)d_in[9];
    const float* efb = (const float*)d_in[10];
    const float* cb = (const float*)d_in[11];
    const float* dfw = (const float*)d_in[12];
    const float* dfb = (const float*)d_in[13];
    const float* dw4 = (const float*)d_in[14];
    const float* db4 = (const float*)d_in[15];
    const float* dw3 = (const float*)d_in[16];
    const float* db3 = (const float*)d_in[17];
    const float* dw2 = (const float*)d_in[18];
    const float* db2 = (const float*)d_in[19];
    const float* dw1 = (const float*)d_in[20];
    const float* db1 = (const float*)d_in[21];
    float* out = (float*)d_out;

    char* wp = (char*)d_ws;
    auto alloc = [&](size_t bytes) {
        char* p = wp;
        wp += (bytes + 255) & ~(size_t)255;
        return p;
    };
    unsigned short* actA_h = (unsigned short*)alloc(33554432);
    unsigned short* actA_l = (unsigned short*)alloc(33554432);
    unsigned short* actB_h = (unsigned short*)alloc(33554432);
    unsigned short* actB_l = (unsigned short*)alloc(33554432);
    float* partial = (float*)actB_h;  // 67.1 MB overlay (free at FC1 time)
    unsigned short* w1h = (unsigned short*)alloc(786432);
    unsigned short* w1l = (unsigned short*)alloc(786432);
    unsigned short* w2h = (unsigned short*)alloc(1572864);
    unsigned short* w2l = (unsigned short*)alloc(1572864);
    unsigned short* w3h = (unsigned short*)alloc(1572864);
    unsigned short* w3l = (unsigned short*)alloc(1572864);
    unsigned short* w4h = (unsigned short*)alloc(1572864);
    unsigned short* w4l = (unsigned short*)alloc(1572864);
    unsigned short* w5h = (unsigned short*)alloc(1572864);
    unsigned short* w5l = (unsigned short*)alloc(1572864);
    unsigned short* w6h = (unsigned short*)alloc(1572864);
    unsigned short* w6l = (unsigned short*)alloc(1572864);
    unsigned short* w7h = (unsigned short*)alloc(1572864);
    unsigned short* w7l = (unsigned short*)alloc(1572864);
    unsigned short* w8h = (unsigned short*)alloc(786432);
    unsigned short* w8l = (unsigned short*)alloc(786432);
    unsigned short* fcwh = (unsigned short*)alloc(16777216);
    unsigned short* fcwl = (unsigned short*)alloc(16777216);
    float* z = (float*)alloc(2097152);
    unsigned short* zqh = (unsigned short*)alloc(1048576);
    unsigned short* zql = (unsigned short*)alloc(1048576);
    float* cnorm = (float*)alloc(32768);
    float* pval = (float*)alloc(262144);
    int* pidx = (int*)alloc(262144);
    int* idx = (int*)alloc(4096);
    float* lsum = (float*)alloc(4096);
    float* dfbp = (float*)alloc(65536);

    // ---- preps ----
    transpose_split<<<1024, 256, 0, stream>>>(x, actA_h, actA_l, 1, 8192, 8192, 256);
    wprep_conv<<<512, 256, 0, stream>>>(ew1, w1h, w1l, 512, 256);
    wprep_conv<<<1024, 256, 0, stream>>>(ew2, w2h, w2l, 512, 512);
    wprep_conv<<<1024, 256, 0, stream>>>(ew3, w3h, w3l, 512, 512);
    wprep_conv<<<1024, 256, 0, stream>>>(ew4, w4h, w4l, 512, 512);
    wprep_deconv<<<1024, 256, 0, stream>>>(dw4, w5h, w5l, 512, 512);
    wprep_deconv<<<1024, 256, 0, stream>>>(dw3, w6h, w6l, 512, 512);
    wprep_deconv<<<1024, 256, 0, stream>>>(dw2, w7h, w7l, 512, 512);
    wprep_deconv<<<512, 256, 0, stream>>>(dw1, w8h, w8l, 256, 512);
    wprep_dfb<<<64, 256, 0, stream>>>(dfb, dfbp);
    transpose_split<<<1024, 256, 0, stream>>>(efw, fcwh, fcwl, 2, 16384, 16384, 512);

    // ---- encoder ----
    conv_mfma<256, 512, false><<<512, 512, 0, stream>>>(actA_h, actA_l, w1h, w1l, eb1,
                                                        actB_h, actB_l, nullptr);
    conv_mfma<512, 512, false><<<512, 512, 0, stream>>>(actB_h, actB_l, w2h, w2l, eb2,
                                                        actA_h, actA_l, nullptr);
    conv_mfma<512, 512, false><<<512, 512, 0, stream>>>(actA_h, actA_l, w3h, w3l, eb3,
                                                        actB_h, actB_l, nullptr);
    conv_mfma<512, 512, false><<<512, 512, 0, stream>>>(actB_h, actB_l, w4h, w4l, eb4,
                                                        actA_h, actA_l, nullptr);
    // enc FC: M=512(e), N=1024(b), K=16384, split-K 32 -> 512 blocks
    fc_mfma<0><<<dim3(8, 2, 32), 512, 0, stream>>>(fcwh, fcwl, actA_h, actA_l, nullptr,
                                                   partial, nullptr, nullptr, 512, 1024,
                                                   16384, 512);
    reduce_bias32<<<512, 256, 0, stream>>>((const float4*)partial, efb, (float4*)z);

    // ---- VQ (fp32) ----
    cnorm_k<<<NE_, 64, 0, stream>>>(cb, cnorm);
    vq_score<<<dim3(64, 8), 256, 0, stream>>>(z, cb, cnorm, pval, pidx);
    vq_final<<<4, 256, 0, stream>>>(pval, pidx, idx);
    zq_loss<<<B_, 128, 0, stream>>>(z, cb, idx, zqh, zql, lsum);
    loss_final<<<1, 256, 0, stream>>>(lsum, out + (size_t)B_ * IN_ * T_);

    // ---- decoder ----
    wprep_dfw<<<4096, 256, 0, stream>>>(dfw, fcwh, fcwl);
    // dec FC: M=16384(f'), N=1024(b), K=512 -> 512 blocks
    fc_mfma<1><<<dim3(8, 64, 1), 512, 0, stream>>>(fcwh, fcwl, zqh, zql, dfbp, nullptr,
                                                   actB_h, actB_l, 16384, 1024, 512, 512);
    conv_mfma<512, 512, false><<<512, 512, 0, stream>>>(actB_h, actB_l, w5h, w5l, db4,
                                                        actA_h, actA_l, nullptr);
    conv_mfma<512, 512, false><<<512, 512, 0, stream>>>(actA_h, actA_l, w6h, w6l, db3,
                                                        actB_h, actB_l, nullptr);
    conv_mfma<512, 512, false><<<512, 512, 0, stream>>>(actB_h, actB_l, w7h, w7l, db2,
                                                        actA_h, actA_l, nullptr);
    conv_mfma<512, 256, true><<<512, 512, 0, stream>>>(actA_h, actA_l, w8h, w8l, db1,
                                                       nullptr, nullptr, out);
}

// Round 5
// 1598.906 us; speedup vs baseline: 1.6816x; 1.6816x over previous
//
#include <hip/hip_runtime.h>
#include <hip/hip_bf16.h>

// VQVAE forward: B=1024, IN=256, H=512, E=512, NE=8192, T=32.
// MFMA split-bf16 (hi/lo) path; blocked weight layout for streaming loads.

#define B_ 1024
#define IN_ 256
#define H_ 512
#define E_ 512
#define NE_ 8192
#define T_ 32

typedef __attribute__((ext_vector_type(8))) short short8;
typedef __attribute__((ext_vector_type(4))) short short4v;
typedef __attribute__((ext_vector_type(4))) float f32x4;

__device__ __forceinline__ unsigned short bf_hi(float v) {
    __hip_bfloat16 h = __float2bfloat16(v);
    return *reinterpret_cast<unsigned short*>(&h);
}
__device__ __forceinline__ float bf_f(unsigned short u) {
    __hip_bfloat16 h;
    *reinterpret_cast<unsigned short*>(&h) = u;
    return __bfloat162float(h);
}
__device__ __forceinline__ void split2(float v, unsigned short& h, unsigned short& l) {
    h = bf_hi(v);
    l = bf_hi(v - bf_f(h));
}

// ---------------- transpose + hi/lo split ----------------
// src: [outer][R=256*chunks][32] fp32 -> dst planes [outer][32][R] bf16 hi/lo
__global__ __launch_bounds__(256) void transpose_split(const float* __restrict__ src,
        unsigned short* __restrict__ dh, unsigned short* __restrict__ dl,
        int chunks, size_t s_outer, size_t d_outer, int d_rstride) {
    __shared__ float xs[256][33];
    const int ch = blockIdx.x % chunks;
    const int ou = blockIdx.x / chunks;
    const int tid = threadIdx.x;
    const float4* s4 = (const float4*)(src + (size_t)ou * s_outer + (size_t)ch * 256 * 32);
#pragma unroll
    for (int q = 0; q < 8; ++q) {
        float4 v = s4[tid * 8 + q];
        xs[tid][q * 4 + 0] = v.x;
        xs[tid][q * 4 + 1] = v.y;
        xs[tid][q * 4 + 2] = v.z;
        xs[tid][q * 4 + 3] = v.w;
    }
    __syncthreads();
    const int t = tid & 31, ig = tid >> 5;
#pragma unroll
    for (int g2 = 0; g2 < 4; ++g2) {
        int i0 = (ig + g2 * 8) * 8;
        short8 hv, lv;
#pragma unroll
        for (int j = 0; j < 8; ++j) {
            float v = xs[i0 + j][t];
            unsigned short hh, ll;
            split2(v, hh, ll);
            hv[j] = (short)hh;
            lv[j] = (short)ll;
        }
        size_t off = (size_t)ou * d_outer + (size_t)ch * 256 + (size_t)t * d_rstride + i0;
        *(short8*)(dh + off) = hv;
        *(short8*)(dl + off) = lv;
    }
}

// ---------------- weight preps (blocked: [tap][kb][o][i%32]) ----------------
__global__ void wprep_conv(const float* __restrict__ w, unsigned short* __restrict__ wh,
                           unsigned short* __restrict__ wl, int O, int I) {
    int t = blockIdx.x * 256 + threadIdx.x;
    if (t < O * I) {
        int o = t / I, i = t - o * I;
        int kb = i >> 5, im = i & 31;
        int KB = I >> 5;
#pragma unroll
        for (int tap = 0; tap < 3; ++tap) {
            float v = w[(size_t)t * 3 + tap];
            unsigned short hh, ll;
            split2(v, hh, ll);
            size_t d = (((size_t)tap * KB + kb) * O + o) * 32 + im;
            wh[d] = hh;
            wl[d] = ll;
        }
    }
}
__global__ void wprep_deconv(const float* __restrict__ w, unsigned short* __restrict__ wh,
                             unsigned short* __restrict__ wl, int O, int I) {
    int t = blockIdx.x * 256 + threadIdx.x;
    if (t < O * I) {
        int o = t / I, i = t - o * I;
        int kb = i >> 5, im = i & 31;
        int KB = I >> 5;
#pragma unroll
        for (int tap = 0; tap < 3; ++tap) {
            float v = w[((size_t)i * O + o) * 3 + 2 - tap];
            unsigned short hh, ll;
            split2(v, hh, ll);
            size_t d = (((size_t)tap * KB + kb) * O + o) * 32 + im;
            wh[d] = hh;
            wl[d] = ll;
        }
    }
}
// dfw (16384,512) f=c*32+t -> blocked [kb=e/32][f'=t*512+c][e%32]
__global__ void wprep_dfw(const float* __restrict__ w, unsigned short* __restrict__ wh,
                          unsigned short* __restrict__ wl) {
    size_t id = (size_t)blockIdx.x * 256 + threadIdx.x;
    int fp = (int)(id >> 6);
    int e8 = ((int)id & 63) * 8;
    int tt = fp >> 9, c = fp & 511;
    int f = c * 32 + tt;
    const float* s = w + (size_t)f * 512 + e8;
    short8 hv, lv;
#pragma unroll
    for (int j = 0; j < 8; ++j) {
        unsigned short hh, ll;
        split2(s[j], hh, ll);
        hv[j] = (short)hh;
        lv[j] = (short)ll;
    }
    size_t d = (((size_t)(e8 >> 5)) * 16384 + fp) * 32 + (e8 & 31);
    *(short8*)(wh + d) = hv;
    *(short8*)(wl + d) = lv;
}
__global__ void wprep_dfb(const float* __restrict__ b, float* __restrict__ bp) {
    int fp = blockIdx.x * 256 + threadIdx.x;
    int tt = fp >> 9, c = fp & 511;
    bp[fp] = b[c * 32 + tt];
}

// ---------------- conv1d via MFMA implicit GEMM ----------------
// Acts: planes [b][t][CIN] hi/lo. Weights blocked [tap][kb][o][i%32] hi/lo.
// Block = NBATCH batches x 256 o-slice; 8 waves = 4 o-tiles x 2 col-halves.
template <int CIN, int COUT, bool FP32OUT>
__global__ __launch_bounds__(512, 2) void conv_mfma(
    const unsigned short* __restrict__ Xh, const unsigned short* __restrict__ Xl,
    const unsigned short* __restrict__ Wh, const unsigned short* __restrict__ Wl,
    const float* __restrict__ bias,
    unsigned short* __restrict__ Yh, unsigned short* __restrict__ Yl,
    float* __restrict__ Yf) {
    constexpr int NSTEP = CIN / 32;
    constexpr int NBATCH = (COUT == 512) ? 8 : 4;
    constexpr int NF = NBATCH;
    constexpr int NROWSL = NBATCH * 34;
    constexpr int U = (NBATCH == 8) ? 4 : 2;
    __shared__ short Bs[2][2][NROWSL][36];

    const int tid = threadIdx.x;
    const int wid = tid >> 6;
    const int lane = tid & 63;
    const int l15 = lane & 15;
    const int lg = lane >> 4;
    const int wo = wid & 3;
    const int wc = wid >> 2;
    const int b0 = blockIdx.x * NBATCH;
    const int o0 = blockIdx.y * 256 + wo * 64;

    // zero pad rows (t=-1 / t=32 per batch, both buffers/planes)
    for (int j = tid; j < 4 * 2 * NBATCH * 36; j += 512) {
        int col = j % 36;
        int r = j / 36;
        int buf = r & 1, pl = (r >> 1) & 1, slot = r >> 2;
        Bs[buf][pl][(slot >> 1) * 34 + (slot & 1) * 33][col] = 0;
    }

    // staging map
    const int plane = tid >> 8;
    int srowr, q0;
    if constexpr (U == 4) {
        srowr = tid & 255;
        q0 = 0;
    } else {
        srowr = (tid & 255) >> 1;
        q0 = (tid & 1) * 2;
    }
    const int sb = srowr >> 5, st = srowr & 31;
    const unsigned short* sptr = (plane ? Xl : Xh) + ((size_t)(b0 + sb) * 32 + st) * CIN;
    const int srow = sb * 34 + 1 + st;

    {
        short8 nv[U];
#pragma unroll
        for (int u = 0; u < U; ++u) nv[u] = *(const short8*)(sptr + (q0 + u) * 8);
#pragma unroll
        for (int u = 0; u < U; ++u) *(short8*)&Bs[0][plane][srow][(q0 + u) * 8] = nv[u];
    }
    __syncthreads();

    f32x4 acc[4][NF];
#pragma unroll
    for (int of = 0; of < 4; ++of)
#pragma unroll
        for (int nf = 0; nf < NF; ++nf) acc[of][nf] = (f32x4){0.f, 0.f, 0.f, 0.f};

    for (int ks = 0; ks < NSTEP; ++ks) {
        const int buf = ks & 1;
        const bool pre = (ks + 1 < NSTEP);
        short8 nv[U];
        if (pre) {
#pragma unroll
            for (int u = 0; u < U; ++u)
                nv[u] = *(const short8*)(sptr + (ks + 1) * 32 + (q0 + u) * 8);
        }
#pragma unroll
        for (int tap = 0; tap < 3; ++tap) {
            short8 Ah[4], Al[4];
#pragma unroll
            for (int of = 0; of < 4; ++of) {
                const size_t wb =
                    (((size_t)tap * NSTEP + ks) * COUT + (o0 + of * 16 + l15)) * 32 + lg * 8;
                Ah[of] = *(const short8*)(Wh + wb);
                Al[of] = *(const short8*)(Wl + wb);
            }
            __builtin_amdgcn_s_setprio(1);
#pragma unroll
            for (int nf = 0; nf < NF; ++nf) {
                const int nfg = wc * NF + nf;
                const int row = (nfg >> 1) * 34 + (nfg & 1) * 16 + tap + l15;
                short8 Bh = *(const short8*)&Bs[buf][0][row][lg * 8];
                short8 Bl = *(const short8*)&Bs[buf][1][row][lg * 8];
#pragma unroll
                for (int of = 0; of < 4; ++of) {
                    acc[of][nf] =
                        __builtin_amdgcn_mfma_f32_16x16x32_bf16(Ah[of], Bh, acc[of][nf], 0, 0, 0);
                    acc[of][nf] =
                        __builtin_amdgcn_mfma_f32_16x16x32_bf16(Ah[of], Bl, acc[of][nf], 0, 0, 0);
                    acc[of][nf] =
                        __builtin_amdgcn_mfma_f32_16x16x32_bf16(Al[of], Bh, acc[of][nf], 0, 0, 0);
                }
            }
            __builtin_amdgcn_s_setprio(0);
        }
        if (pre) {
#pragma unroll
            for (int u = 0; u < U; ++u)
                *(short8*)&Bs[buf ^ 1][plane][srow][(q0 + u) * 8] = nv[u];
            __syncthreads();
        }
    }

    // epilogue: lane holds cols n (per nf), rows m = o0 + of*16 + 4*lg + r
#pragma unroll
    for (int of = 0; of < 4; ++of) {
        const int m4 = o0 + of * 16 + lg * 4;
        float4 bv = *(const float4*)(bias + m4);
        float bva[4] = {bv.x, bv.y, bv.z, bv.w};
#pragma unroll
        for (int nf = 0; nf < NF; ++nf) {
            const int n = (wc * NF + nf) * 16 + l15;
            const int gb = b0 + (n >> 5);
            const int t = n & 31;
            if (FP32OUT) {
#pragma unroll
                for (int r = 0; r < 4; ++r) {
                    float v = acc[of][nf][r] + bva[r];
                    Yf[((size_t)gb * COUT + m4 + r) * 32 + t] = v;
                }
            } else {
                short4v hv, lv;
#pragma unroll
                for (int r = 0; r < 4; ++r) {
                    float v = fmaxf(acc[of][nf][r] + bva[r], 0.f);
                    unsigned short hh, ll;
                    split2(v, hh, ll);
                    hv[r] = (short)hh;
                    lv[r] = (short)ll;
                }
                const size_t off = ((size_t)gb * 32 + t) * COUT + m4;
                *(short4v*)(Yh + off) = hv;
                *(short4v*)(Yl + off) = lv;
            }
        }
    }
}

// ---------------- FC via MFMA (global-fragment GEMM-TN) ----------------
// C[m,n] = sum_k A[m,k]*B[n,k], 3-term split. Block: 256 m x 128 n, 8 waves.
// ABLK: A stored blocked [kb][m][k%32]. MODE 0: fp32 partial [kz][n][m];
// MODE 1: +bias, hi/lo out [n][m].
template <int MODE, bool ABLK>
__global__ __launch_bounds__(512) void fc_mfma(
    const unsigned short* __restrict__ Ah_, const unsigned short* __restrict__ Al_,
    const unsigned short* __restrict__ Bh_, const unsigned short* __restrict__ Bl_,
    const float* __restrict__ bias, float* __restrict__ Pf,
    unsigned short* __restrict__ Oh, unsigned short* __restrict__ Ol,
    int M, int N, int K, int kc) {
    const int tid = threadIdx.x;
    const int wid = tid >> 6;
    const int lane = tid & 63;
    const int l15 = lane & 15;
    const int lg = lane >> 4;
    const int m0 = blockIdx.y * 256 + (wid & 3) * 64;
    const int n0 = blockIdx.x * 128 + (wid >> 2) * 64;
    const int k0b = blockIdx.z * kc;

    f32x4 acc[4][4];
#pragma unroll
    for (int of = 0; of < 4; ++of)
#pragma unroll
        for (int nf = 0; nf < 4; ++nf) acc[of][nf] = (f32x4){0.f, 0.f, 0.f, 0.f};

    for (int k0 = k0b; k0 < k0b + kc; k0 += 32) {
        short8 Ah[4], Al[4];
#pragma unroll
        for (int of = 0; of < 4; ++of) {
            const size_t ao = ABLK
                ? (((size_t)(k0 >> 5)) * M + (m0 + of * 16 + l15)) * 32 + lg * 8
                : (size_t)(m0 + of * 16 + l15) * K + k0 + lg * 8;
            Ah[of] = *(const short8*)(Ah_ + ao);
            Al[of] = *(const short8*)(Al_ + ao);
        }
#pragma unroll
        for (int nf = 0; nf < 4; ++nf) {
            const size_t bo = (size_t)(n0 + nf * 16 + l15) * K + k0 + lg * 8;
            short8 Bh = *(const short8*)(Bh_ + bo);
            short8 Bl = *(const short8*)(Bl_ + bo);
#pragma unroll
            for (int of = 0; of < 4; ++of) {
                acc[of][nf] =
                    __builtin_amdgcn_mfma_f32_16x16x32_bf16(Ah[of], Bh, acc[of][nf], 0, 0, 0);
                acc[of][nf] =
                    __builtin_amdgcn_mfma_f32_16x16x32_bf16(Ah[of], Bl, acc[of][nf], 0, 0, 0);
                acc[of][nf] =
                    __builtin_amdgcn_mfma_f32_16x16x32_bf16(Al[of], Bh, acc[of][nf], 0, 0, 0);
            }
        }
    }

#pragma unroll
    for (int of = 0; of < 4; ++of) {
        const int m4 = m0 + of * 16 + lg * 4;
        if (MODE == 0) {
#pragma unroll
            for (int nf = 0; nf < 4; ++nf) {
                const int n = n0 + nf * 16 + l15;
                *(f32x4*)(Pf + ((size_t)blockIdx.z * N + n) * M + m4) = acc[of][nf];
            }
        } else {
            float4 bv = *(const float4*)(bias + m4);
            float bva[4] = {bv.x, bv.y, bv.z, bv.w};
#pragma unroll
            for (int nf = 0; nf < 4; ++nf) {
                const int n = n0 + nf * 16 + l15;
                short4v hv, lv;
#pragma unroll
                for (int r = 0; r < 4; ++r) {
                    float v = acc[of][nf][r] + bva[r];
                    unsigned short hh, ll;
                    split2(v, hh, ll);
                    hv[r] = (short)hh;
                    lv[r] = (short)ll;
                }
                *(short4v*)(Oh + (size_t)n * M + m4) = hv;
                *(short4v*)(Ol + (size_t)n * M + m4) = lv;
            }
        }
    }
}

// sum 32 split-K partials [kz][b][e] + bias -> z [b][e]
__global__ void reduce_bias32(const float4* __restrict__ part, const float* __restrict__ bias,
                              float4* __restrict__ z) {
    int t = blockIdx.x * 256 + threadIdx.x;
    const size_t stride = (size_t)B_ * E_ / 4;
    float4 a = part[t];
#pragma unroll 4
    for (int s = 1; s < 32; ++s) {
        float4 p = part[(size_t)s * stride + t];
        a.x += p.x;
        a.y += p.y;
        a.z += p.z;
        a.w += p.w;
    }
    float4 bv = ((const float4*)bias)[t & (E_ / 4 - 1)];
    a.x += bv.x;
    a.y += bv.y;
    a.z += bv.z;
    a.w += bv.w;
    z[t] = a;
}

// ---------------- VQ (fp32, validated) ----------------
__global__ void cnorm_k(const float* __restrict__ cb, float* __restrict__ cnorm) {
    int n = blockIdx.x;
    int l = threadIdx.x;
    const float4* row = (const float4*)(cb + (size_t)n * E_);
    float s = 0.f;
#pragma unroll
    for (int q = 0; q < 2; ++q) {
        float4 v = row[l + q * 64];
        s += v.x * v.x + v.y * v.y + v.z * v.z + v.w * v.w;
    }
#pragma unroll
    for (int off = 32; off; off >>= 1) s += __shfl_down(s, off);
    if (l == 0) cnorm[n] = s;
}

__global__ __launch_bounds__(256) void vq_score(const float* __restrict__ z,
                                                const float* __restrict__ cb,
                                                const float* __restrict__ cnorm,
                                                float* __restrict__ pval, int* __restrict__ pidx) {
    __shared__ __align__(16) float smem[2 * 16 * 132];
    float(*As)[132] = (float(*)[132])smem;
    float(*Bsh)[132] = (float(*)[132])(smem + 16 * 132);
    const int n0 = blockIdx.x * 128;
    const int m0 = blockIdx.y * 128;
    const int tid = threadIdx.x;
    const int tx = tid & 15;
    const int ty = tid >> 4;
    float acc[8][8] = {};

    for (int k0 = 0; k0 < E_; k0 += 16) {
#pragma unroll
        for (int l = 0; l < 2; ++l) {
            int t = tid + l * 256;
            int r = t >> 2;
            int c = (t & 3) << 2;
            float4 va = *(const float4*)(z + (size_t)(m0 + r) * E_ + k0 + c);
            As[c + 0][r] = va.x;
            As[c + 1][r] = va.y;
            As[c + 2][r] = va.z;
            As[c + 3][r] = va.w;
            float4 vb = *(const float4*)(cb + (size_t)(n0 + r) * E_ + k0 + c);
            Bsh[c + 0][r] = vb.x;
            Bsh[c + 1][r] = vb.y;
            Bsh[c + 2][r] = vb.z;
            Bsh[c + 3][r] = vb.w;
        }
        __syncthreads();
#pragma unroll
        for (int k = 0; k < 16; ++k) {
            float a[8], b[8];
            *(float4*)&a[0] = *(const float4*)&As[k][ty * 8];
            *(float4*)&a[4] = *(const float4*)&As[k][ty * 8 + 4];
            *(float4*)&b[0] = *(const float4*)&Bsh[k][tx * 8];
            *(float4*)&b[4] = *(const float4*)&Bsh[k][tx * 8 + 4];
#pragma unroll
            for (int i = 0; i < 8; ++i)
#pragma unroll
                for (int j = 0; j < 8; ++j) acc[i][j] += a[i] * b[j];
        }
        __syncthreads();
    }

    float* sv = smem;
    int* si = (int*)(smem + 16 * 132);
    float cn[8];
    *(float4*)&cn[0] = *(const float4*)(cnorm + n0 + tx * 8);
    *(float4*)&cn[4] = *(const float4*)(cnorm + n0 + tx * 8 + 4);
#pragma unroll
    for (int i = 0; i < 8; ++i) {
        int row = ty * 8 + i;
        float bvv = -3.4e38f;
        int bn = 0;
#pragma unroll
        for (int j = 0; j < 8; ++j) {
            float v = 2.f * acc[i][j] - cn[j];
            if (v > bvv) {
                bvv = v;
                bn = n0 + tx * 8 + j;
            }
        }
        sv[row * 16 + tx] = bvv;
        si[row * 16 + tx] = bn;
    }
    __syncthreads();
    if (tid < 128) {
        float bvv = sv[tid * 16];
        int bn = si[tid * 16];
#pragma unroll
        for (int t = 1; t < 16; ++t) {
            float v = sv[tid * 16 + t];
            if (v > bvv) {
                bvv = v;
                bn = si[tid * 16 + t];
            }
        }
        pval[(size_t)(m0 + tid) * 64 + blockIdx.x] = bvv;
        pidx[(size_t)(m0 + tid) * 64 + blockIdx.x] = bn;
    }
}

__global__ void vq_final(const float* __restrict__ pval, const int* __restrict__ pidx,
                         int* __restrict__ idx) {
    int b = blockIdx.x * 256 + threadIdx.x;
    if (b < B_) {
        const float* pv = pval + (size_t)b * 64;
        const int* pi = pidx + (size_t)b * 64;
        float bvv = pv[0];
        int bn = pi[0];
        for (int t = 1; t < 64; ++t) {
            float v = pv[t];
            if (v > bvv) {
                bvv = v;
                bn = pi[t];
            }
        }
        idx[b] = bn;
    }
}

__global__ __launch_bounds__(128) void zq_loss(const float* __restrict__ z,
                                               const float* __restrict__ cb,
                                               const int* __restrict__ idx,
                                               unsigned short* __restrict__ zqh,
                                               unsigned short* __restrict__ zql,
                                               float* __restrict__ lsum) {
    int b = blockIdx.x;
    int t = threadIdx.x;
    int id = idx[b];
    float4 c = ((const float4*)(cb + (size_t)id * E_))[t];
    float4 zv = ((const float4*)(z + (size_t)b * E_))[t];
    float ca[4] = {c.x, c.y, c.z, c.w};
    short4v hv, lv;
#pragma unroll
    for (int r = 0; r < 4; ++r) {
        unsigned short hh, ll;
        split2(ca[r], hh, ll);
        hv[r] = (short)hh;
        lv[r] = (short)ll;
    }
    *(short4v*)(zqh + (size_t)b * E_ + t * 4) = hv;
    *(short4v*)(zql + (size_t)b * E_ + t * 4) = lv;
    float dx = c.x - zv.x, dy = c.y - zv.y, dz = c.z - zv.z, dw = c.w - zv.w;
    float s = dx * dx + dy * dy + dz * dz + dw * dw;
#pragma unroll
    for (int off = 32; off; off >>= 1) s += __shfl_down(s, off);
    __shared__ float w2[2];
    if ((t & 63) == 0) w2[t >> 6] = s;
    __syncthreads();
    if (t == 0) lsum[b] = w2[0] + w2[1];
}

__global__ void loss_final(const float* __restrict__ lsum, float* __restrict__ out) {
    __shared__ float sm[256];
    float s = 0.f;
    for (int i = threadIdx.x; i < B_; i += 256) s += lsum[i];
    sm[threadIdx.x] = s;
    __syncthreads();
    for (int off = 128; off; off >>= 1) {
        if (threadIdx.x < off) sm[threadIdx.x] += sm[threadIdx.x + off];
        __syncthreads();
    }
    if (threadIdx.x == 0) out[0] = 1.25f * sm[0] / (float)(B_ * E_);
}

// ---------------- launcher ----------------
extern "C" void kernel_launch(void* const* d_in, const int* in_sizes, int n_in,
                              void* d_out, int out_size, void* d_ws, size_t ws_size,
                              hipStream_t stream) {
    const float* x = (const float*)d_in[0];
    const float* ew1 = (const float*)d_in[1];
    const float* eb1 = (const float*)d_in[2];
    const float* ew2 = (const float*)d_in[3];
    const float* eb2 = (const float*)d_in[4];
    const float* ew3 = (const float*)d_in[5];
    const float* eb3 = (const float*)d_in[6];
    const float* ew4 = (const float*)d_in[7];
    const float* eb4 = (const float*)d_in[8];
    const float* efw = (const float*)d_in[9];
    const float* efb = (const float*)d_in[10];
    const float* cb = (const float*)d_in[11];
    const float* dfw = (const float*)d_in[12];
    const float* dfb = (const float*)d_in[13];
    const float* dw4 = (const float*)d_in[14];
    const float* db4 = (const float*)d_in[15];
    const float* dw3 = (const float*)d_in[16];
    const float* db3 = (const float*)d_in[17];
    const float* dw2 = (const float*)d_in[18];
    const float* db2 = (const float*)d_in[19];
    const float* dw1 = (const float*)d_in[20];
    const float* db1 = (const float*)d_in[21];
    float* out = (float*)d_out;

    char* wp = (char*)d_ws;
    auto alloc = [&](size_t bytes) {
        char* p = wp;
        wp += (bytes + 255) & ~(size_t)255;
        return p;
    };
    unsigned short* actA_h = (unsigned short*)alloc(33554432);
    unsigned short* actA_l = (unsigned short*)alloc(33554432);
    unsigned short* actB_h = (unsigned short*)alloc(33554432);
    unsigned short* actB_l = (unsigned short*)alloc(33554432);
    float* partial = (float*)actB_h;  // 67.1 MB overlay (free at FC1 time)
    unsigned short* w1h = (unsigned short*)alloc(786432);
    unsigned short* w1l = (unsigned short*)alloc(786432);
    unsigned short* w2h = (unsigned short*)alloc(1572864);
    unsigned short* w2l = (unsigned short*)alloc(1572864);
    unsigned short* w3h = (unsigned short*)alloc(1572864);
    unsigned short* w3l = (unsigned short*)alloc(1572864);
    unsigned short* w4h = (unsigned short*)alloc(1572864);
    unsigned short* w4l = (unsigned short*)alloc(1572864);
    unsigned short* w5h = (unsigned short*)alloc(1572864);
    unsigned short* w5l = (unsigned short*)alloc(1572864);
    unsigned short* w6h = (unsigned short*)alloc(1572864);
    unsigned short* w6l = (unsigned short*)alloc(1572864);
    unsigned short* w7h = (unsigned short*)alloc(1572864);
    unsigned short* w7l = (unsigned short*)alloc(1572864);
    unsigned short* w8h = (unsigned short*)alloc(786432);
    unsigned short* w8l = (unsigned short*)alloc(786432);
    unsigned short* fcwh = (unsigned short*)alloc(16777216);
    unsigned short* fcwl = (unsigned short*)alloc(16777216);
    float* z = (float*)alloc(2097152);
    unsigned short* zqh = (unsigned short*)alloc(1048576);
    unsigned short* zql = (unsigned short*)alloc(1048576);
    float* cnorm = (float*)alloc(32768);
    float* pval = (float*)alloc(262144);
    int* pidx = (int*)alloc(262144);
    int* idx = (int*)alloc(4096);
    float* lsum = (float*)alloc(4096);
    float* dfbp = (float*)alloc(65536);

    // ---- preps ----
    transpose_split<<<1024, 256, 0, stream>>>(x, actA_h, actA_l, 1, 8192, 8192, 256);
    wprep_conv<<<512, 256, 0, stream>>>(ew1, w1h, w1l, 512, 256);
    wprep_conv<<<1024, 256, 0, stream>>>(ew2, w2h, w2l, 512, 512);
    wprep_conv<<<1024, 256, 0, stream>>>(ew3, w3h, w3l, 512, 512);
    wprep_conv<<<1024, 256, 0, stream>>>(ew4, w4h, w4l, 512, 512);
    wprep_deconv<<<1024, 256, 0, stream>>>(dw4, w5h, w5l, 512, 512);
    wprep_deconv<<<1024, 256, 0, stream>>>(dw3, w6h, w6l, 512, 512);
    wprep_deconv<<<1024, 256, 0, stream>>>(dw2, w7h, w7l, 512, 512);
    wprep_deconv<<<512, 256, 0, stream>>>(dw1, w8h, w8l, 256, 512);
    wprep_dfb<<<64, 256, 0, stream>>>(dfb, dfbp);
    transpose_split<<<1024, 256, 0, stream>>>(efw, fcwh, fcwl, 2, 16384, 16384, 512);

    // ---- encoder ----
    conv_mfma<256, 512, false><<<dim3(128, 2), 512, 0, stream>>>(actA_h, actA_l, w1h, w1l,
                                                                 eb1, actB_h, actB_l, nullptr);
    conv_mfma<512, 512, false><<<dim3(128, 2), 512, 0, stream>>>(actB_h, actB_l, w2h, w2l,
                                                                 eb2, actA_h, actA_l, nullptr);
    conv_mfma<512, 512, false><<<dim3(128, 2), 512, 0, stream>>>(actA_h, actA_l, w3h, w3l,
                                                                 eb3, actB_h, actB_l, nullptr);
    conv_mfma<512, 512, false><<<dim3(128, 2), 512, 0, stream>>>(actB_h, actB_l, w4h, w4l,
                                                                 eb4, actA_h, actA_l, nullptr);
    // enc FC: M=512(e), N=1024(b), K=16384, split-K 32 -> 512 blocks
    fc_mfma<0, false><<<dim3(8, 2, 32), 512, 0, stream>>>(fcwh, fcwl, actA_h, actA_l, nullptr,
                                                          partial, nullptr, nullptr, 512, 1024,
                                                          16384, 512);
    reduce_bias32<<<512, 256, 0, stream>>>((const float4*)partial, efb, (float4*)z);

    // ---- VQ (fp32) ----
    cnorm_k<<<NE_, 64, 0, stream>>>(cb, cnorm);
    vq_score<<<dim3(64, 8), 256, 0, stream>>>(z, cb, cnorm, pval, pidx);
    vq_final<<<4, 256, 0, stream>>>(pval, pidx, idx);
    zq_loss<<<B_, 128, 0, stream>>>(z, cb, idx, zqh, zql, lsum);
    loss_final<<<1, 256, 0, stream>>>(lsum, out + (size_t)B_ * IN_ * T_);

    // ---- decoder ----
    wprep_dfw<<<4096, 256, 0, stream>>>(dfw, fcwh, fcwl);
    // dec FC: M=16384(f'), N=1024(b), K=512 -> 512 blocks, blocked A
    fc_mfma<1, true><<<dim3(8, 64, 1), 512, 0, stream>>>(fcwh, fcwl, zqh, zql, dfbp, nullptr,
                                                         actB_h, actB_l, 16384, 1024, 512, 512);
    conv_mfma<512, 512, false><<<dim3(128, 2), 512, 0, stream>>>(actB_h, actB_l, w5h, w5l,
                                                                 db4, actA_h, actA_l, nullptr);
    conv_mfma<512, 512, false><<<dim3(128, 2), 512, 0, stream>>>(actA_h, actA_l, w6h, w6l,
                                                                 db3, actB_h, actB_l, nullptr);
    conv_mfma<512, 512, false><<<dim3(128, 2), 512, 0, stream>>>(actB_h, actB_l, w7h, w7l,
                                                                 db2, actA_h, actA_l, nullptr);
    conv_mfma<512, 256, true><<<dim3(256, 1), 512, 0, stream>>>(actA_h, actA_l, w8h, w8l,
                                                                db1, nullptr, nullptr, out);
}